// Round 1
// baseline (275.101 us; speedup 1.0000x reference)
//
#include <hip/hip_runtime.h>

#define IN_N  8192
#define OUT_N 8186
#define KS    7
#define BX    128   // output tile width per block
#define BY    32    // output tile height per block
#define TPX   32
#define TPY   8
#define RX    4     // outputs per thread in x
#define RY    4     // outputs per thread in y
#define LDS_W 136   // 134 needed, padded to multiple of 4
#define LDS_H 38    // 32 + 6 halo

__global__ __launch_bounds__(256)
void conv7x7_kernel(const float* __restrict__ X, const float* __restrict__ K,
                    const float* __restrict__ bias, float* __restrict__ out) {
    __shared__ float s_in[LDS_H * LDS_W];

    const int tx  = threadIdx.x;          // 0..31
    const int ty  = threadIdx.y;          // 0..7
    const int tid = ty * TPX + tx;        // 0..255
    const int bx0 = blockIdx.x * BX;
    const int by0 = blockIdx.y * BY;

    // ---- Stage input tile (38 rows x 136 cols, 134 used) into LDS via float4 ----
    const int NF4 = LDS_H * (LDS_W / 4);  // 38 * 34 = 1292
    for (int i = tid; i < NF4; i += 256) {
        const int row = i / (LDS_W / 4);
        const int c4  = i % (LDS_W / 4);
        const int gy  = by0 + row;
        const int gx  = bx0 + c4 * 4;
        float4 v;
        if (gy < IN_N && gx + 3 < IN_N) {
            v = *reinterpret_cast<const float4*>(&X[(size_t)gy * IN_N + gx]);
        } else {
            v.x = (gy < IN_N && gx + 0 < IN_N) ? X[(size_t)gy * IN_N + gx + 0] : 0.0f;
            v.y = (gy < IN_N && gx + 1 < IN_N) ? X[(size_t)gy * IN_N + gx + 1] : 0.0f;
            v.z = (gy < IN_N && gx + 2 < IN_N) ? X[(size_t)gy * IN_N + gx + 2] : 0.0f;
            v.w = (gy < IN_N && gx + 3 < IN_N) ? X[(size_t)gy * IN_N + gx + 3] : 0.0f;
        }
        *reinterpret_cast<float4*>(&s_in[row * LDS_W + c4 * 4]) = v;
    }
    __syncthreads();

    // ---- Kernel weights: uniform loads -> SGPRs ----
    float kv[KS * KS];
    #pragma unroll
    for (int i = 0; i < KS * KS; ++i) kv[i] = K[i];
    const float b = bias[0];

    float acc[RY][RX];
    #pragma unroll
    for (int r = 0; r < RY; ++r)
        #pragma unroll
        for (int c = 0; c < RX; ++c) acc[r][c] = b;

    const int xbase = tx * RX;   // column offset within tile
    const int ybase = ty * RY;   // row offset within tile

    // ---- Main compute: 10 input rows per thread, register sliding window ----
    #pragma unroll
    for (int s = 0; s < RY + KS - 1; ++s) {   // 10 rows
        const float* p = &s_in[(ybase + s) * LDS_W + xbase];
        float4 a0 = *reinterpret_cast<const float4*>(p);
        float4 a1 = *reinterpret_cast<const float4*>(p + 4);
        float4 a2 = *reinterpret_cast<const float4*>(p + 8);
        float in12[12] = {a0.x, a0.y, a0.z, a0.w,
                          a1.x, a1.y, a1.z, a1.w,
                          a2.x, a2.y, a2.z, a2.w};
        #pragma unroll
        for (int ky = 0; ky < KS; ++ky) {
            const int r = s - ky;
            if (r >= 0 && r < RY) {
                #pragma unroll
                for (int kx = 0; kx < KS; ++kx) {
                    #pragma unroll
                    for (int c = 0; c < RX; ++c) {
                        acc[r][c] += in12[c + kx] * kv[ky * KS + kx];
                    }
                }
            }
        }
    }

    // ---- Store (float2: rows have pitch 8186 ≡ 2 mod 4, ox multiple of 4 -> 8B aligned) ----
    #pragma unroll
    for (int r = 0; r < RY; ++r) {
        const int oy = by0 + ybase + r;
        if (oy >= OUT_N) continue;
        const int ox = bx0 + xbase;
        float* po = &out[(size_t)oy * OUT_N + ox];
        if (ox + 3 < OUT_N) {
            float2 v0 = make_float2(acc[r][0], acc[r][1]);
            float2 v1 = make_float2(acc[r][2], acc[r][3]);
            *reinterpret_cast<float2*>(po)     = v0;
            *reinterpret_cast<float2*>(po + 2) = v1;
        } else {
            #pragma unroll
            for (int c = 0; c < RX; ++c)
                if (ox + c < OUT_N) po[c] = acc[r][c];
        }
    }
}

extern "C" void kernel_launch(void* const* d_in, const int* in_sizes, int n_in,
                              void* d_out, int out_size, void* d_ws, size_t ws_size,
                              hipStream_t stream) {
    const float* X    = (const float*)d_in[0];
    const float* K    = (const float*)d_in[1];
    const float* bias = (const float*)d_in[2];
    float* out = (float*)d_out;

    dim3 block(TPX, TPY);
    dim3 grid((OUT_N + BX - 1) / BX, (OUT_N + BY - 1) / BY);
    conv7x7_kernel<<<grid, block, 0, stream>>>(X, K, bias, out);
}

// Round 2
// 207.747 us; speedup vs baseline: 1.3242x; 1.3242x over previous
//
#include <hip/hip_runtime.h>

#define IN_N   8192
#define OUT_N  8186
#define KS     7
#define BX     128
#define BY     32
#define TPX    32
#define TPY    8
#define RX     4
#define RY     4
#define LDS_W  136            // floats per LDS row (34 granules of 16 B)
#define LDS_H  38             // 32 + 6 halo
#define GPR    34             // 16B granules per row
#define NSLOT  (LDS_H * GPR)  // 1292 granules per tile
#define NSTEP  4
#define SEG_ROWS (BY * NSTEP) // 128 output rows per block
#define NSEG   64
#define NSTRIP 64

typedef const __attribute__((address_space(1))) unsigned int* gas1_t;
typedef __attribute__((address_space(3))) unsigned int* las3_t;

__device__ __forceinline__ void gll16(const float* g, float* l) {
    // LDS dest: wave-uniform base + lane*16 (guide §5); global src per-lane.
    __builtin_amdgcn_global_load_lds((gas1_t)(const void*)g, (las3_t)(void*)l, 16, 0, 0);
}

__device__ __forceinline__ void store2(float* p, float a, float b) {
    // exactly one vmcnt event, guaranteed count for the s_waitcnt vmcnt(8) math
    union { float f[2]; unsigned long long u; } v;
    v.f[0] = a; v.f[1] = b;
    asm volatile("global_store_dwordx2 %0, %1, off" :: "v"(p), "v"(v.u) : "memory");
}

// Interior staging: 5 full rounds (256 granules) + wave-0 tail (64 granules,
// partially overlapping -> benign duplicate writes of identical data).
// Per-wave global_load_lds count: wave0=6, waves1-3=5.
__device__ __forceinline__ void stage_interior(const float* __restrict__ X,
                                               float* buf, int bx0, int gy0, int tid) {
    #pragma unroll
    for (int k = 0; k < 5; ++k) {
        const int slot = k * 256 + tid;
        const int row  = slot / GPR;
        const int c4   = slot - row * GPR;
        const float* src = X + (size_t)(gy0 + row) * IN_N + (bx0 + c4 * 4);
        gll16(src, buf + (size_t)(k * 256 + (tid & ~63)) * 4);
    }
    if (tid < 64) {
        const int base = NSLOT - 64;          // 1228
        const int slot = base + tid;
        const int row  = slot / GPR;
        const int c4   = slot - row * GPR;
        const float* src = X + (size_t)(gy0 + row) * IN_N + (bx0 + c4 * 4);
        gll16(src, buf + (size_t)base * 4);
    }
}

template <bool GUARD>
__device__ __forceinline__ void compute_store(
    const float* buf, const float* kv, float bias,
    float* __restrict__ out, int oy0, int ox0, int ybase, int xbase)
{
    float acc[RY][RX];
    #pragma unroll
    for (int r = 0; r < RY; ++r)
        #pragma unroll
        for (int c = 0; c < RX; ++c) acc[r][c] = bias;

    #pragma unroll
    for (int s = 0; s < RY + KS - 1; ++s) {      // 10 input rows
        const float* p = buf + (ybase + s) * LDS_W + xbase;
        float4 a0 = *(const float4*)(p);
        float4 a1 = *(const float4*)(p + 4);
        float4 a2 = *(const float4*)(p + 8);
        const float in12[12] = {a0.x, a0.y, a0.z, a0.w,
                                a1.x, a1.y, a1.z, a1.w,
                                a2.x, a2.y, a2.z, a2.w};
        #pragma unroll
        for (int ky = 0; ky < KS; ++ky) {
            const int r = s - ky;
            if (r >= 0 && r < RY) {
                #pragma unroll
                for (int kx = 0; kx < KS; ++kx) {
                    const float w = kv[ky * KS + kx];
                    #pragma unroll
                    for (int c = 0; c < RX; ++c)
                        acc[r][c] += in12[c + kx] * w;
                }
            }
        }
    }

    #pragma unroll
    for (int r = 0; r < RY; ++r) {
        const int oy = oy0 + ybase + r;
        const int ox = ox0 + xbase;
        if constexpr (GUARD) {
            if (oy < OUT_N) {
                #pragma unroll
                for (int c = 0; c < RX; ++c)
                    if (ox + c < OUT_N) out[(size_t)oy * OUT_N + ox + c] = acc[r][c];
            }
        } else {
            float* po = out + (size_t)oy * OUT_N + ox;
            store2(po,     acc[r][0], acc[r][1]);
            store2(po + 2, acc[r][2], acc[r][3]);
        }
    }
}

__global__ __launch_bounds__(256, 3)
void conv7x7_pipe(const float* __restrict__ X, const float* __restrict__ K,
                  const float* __restrict__ bias, float* __restrict__ out) {
    __shared__ float s0[LDS_H * LDS_W];
    __shared__ float s1[LDS_H * LDS_W];

    const int tx = threadIdx.x, ty = threadIdx.y;
    const int tid = ty * TPX + tx;
    const int strip = blockIdx.x, seg = blockIdx.y;
    const int bx0 = strip * BX;
    const int iy0 = seg * SEG_ROWS;
    const int xbase = tx * RX, ybase = ty * RY;

    float kv[KS * KS];
    #pragma unroll
    for (int i = 0; i < KS * KS; ++i) kv[i] = K[i];
    const float b = bias[0];

    if (strip < NSTRIP - 1 && seg < NSEG - 1) {
        // -------- interior: double-buffered async pipeline, 1 barrier/step --------
        stage_interior(X, s0, bx0, iy0, tid);
        asm volatile("s_waitcnt vmcnt(0)" ::: "memory");
        __builtin_amdgcn_s_barrier();
        __builtin_amdgcn_sched_barrier(0);

        #pragma unroll 1
        for (int t0 = 0; t0 < NSTEP; t0 += 2) {
            // phase A: stage s1(t0+1) in flight under compute of s0(t0)
            stage_interior(X, s1, bx0, iy0 + (t0 + 1) * BY, tid);
            compute_store<false>(s0, kv, b, out, iy0 + t0 * BY, bx0, ybase, xbase);
            // queue per wave: [<=6 loads, 8 asm stores]; <=8 left => loads retired
            asm volatile("s_waitcnt vmcnt(8)" ::: "memory");
            __builtin_amdgcn_s_barrier();
            __builtin_amdgcn_sched_barrier(0);

            // phase B
            if (t0 + 2 < NSTEP)
                stage_interior(X, s0, bx0, iy0 + (t0 + 2) * BY, tid);
            compute_store<false>(s1, kv, b, out, iy0 + (t0 + 1) * BY, bx0, ybase, xbase);
            if (t0 + 2 < NSTEP) {
                asm volatile("s_waitcnt vmcnt(8)" ::: "memory");
                __builtin_amdgcn_s_barrier();
                __builtin_amdgcn_sched_barrier(0);
            }
        }
        asm volatile("s_waitcnt vmcnt(0)" ::: "memory");  // drain asm stores before endpgm
    } else {
        // -------- boundary (127/4096 blocks): simple guarded single-buffer path ----
        for (int t = 0; t < NSTEP; ++t) {
            const int gy0 = iy0 + t * BY;
            __syncthreads();                    // previous step's readers done
            #pragma unroll
            for (int k = 0; k < 6; ++k) {
                const int slot = k * 256 + tid;
                if (slot < NSLOT) {
                    const int row = slot / GPR;
                    const int c4  = slot - row * GPR;
                    const int gy = min(gy0 + row, IN_N - 1);
                    const int gx = min(bx0 + c4 * 4, IN_N - 4);   // clamped garbage only feeds discarded outputs
                    *(float4*)&s0[row * LDS_W + c4 * 4] =
                        *(const float4*)&X[(size_t)gy * IN_N + gx];
                }
            }
            __syncthreads();
            compute_store<true>(s0, kv, b, out, gy0, bx0, ybase, xbase);
        }
    }
}

extern "C" void kernel_launch(void* const* d_in, const int* in_sizes, int n_in,
                              void* d_out, int out_size, void* d_ws, size_t ws_size,
                              hipStream_t stream) {
    const float* X    = (const float*)d_in[0];
    const float* K    = (const float*)d_in[1];
    const float* bias = (const float*)d_in[2];
    float* out = (float*)d_out;

    dim3 block(TPX, TPY);
    dim3 grid(NSTRIP, NSEG);
    conv7x7_pipe<<<grid, block, 0, stream>>>(X, K, bias, out);
}

// Round 3
// 146.689 us; speedup vs baseline: 1.8754x; 1.4162x over previous
//
#include <hip/hip_runtime.h>
#include <hip/hip_bf16.h>

#define IN_N   8192
#define OUT_N  8186
#define KS     7

#define BXO    128            // output cols per block tile
#define BYO    64             // output rows per step
#define IC     144            // staged input cols = BXO + 16 (A reads k to 31)
#define IR     70             // staged input rows = BYO + 6
#define LSTR   304            // LDS bytes/row: 144*2=288 + 16 pad (bank-balanced: 304/4 % 32 = 12)
#define GPR    36             // float4 granules per staged row (144/4)
#define NGRAN  (IR * GPR)     // 2520
#define NLD    10             // ceil(2520/256) load rounds
#define NSTEP  4
#define NSTRIP 64             // 64*128 = 8192 >= 8186
#define NSEG   32             // 32*256  = 8192 >= 8186

typedef __bf16 bf16x8 __attribute__((ext_vector_type(8)));
typedef float  f32x4  __attribute__((ext_vector_type(4)));

union BFU { __bf16 h; unsigned short u; };
__device__ __forceinline__ unsigned short f2bf(float f) {
    BFU c; c.h = (__bf16)f; return c.u;       // RNE; compiler fuses pairs to v_cvt_pk_bf16_f32
}

template<bool GUARD>
__device__ __forceinline__ void run_block(
    const float* __restrict__ X, const float* __restrict__ Kw,
    const float* __restrict__ bias, float* __restrict__ out,
    char* sb0, char* sb1, int X0, int ybase, int tid)
{
    const int lane = tid & 63;
    const int w    = tid >> 6;    // wave id: owns output rows 16w..16w+15 of each step tile
    const int lo   = lane & 15;
    const int hi   = lane >> 4;

    // ---- constant Toeplitz B fragments: B[k][j] = w[ky][k-j], k=8*hi+e, j=lo ----
    // A and B use the SAME (lane,e)->k convention, so any HW k-permutation cancels.
    bf16x8 bfrag[KS];
    #pragma unroll
    for (int ky = 0; ky < KS; ++ky) {
        bf16x8 bv;
        #pragma unroll
        for (int e = 0; e < 8; ++e) {
            const int d = 8*hi + e - lo;
            const float v = (d >= 0 && d < KS) ? Kw[ky*KS + d] : 0.0f;
            bv[e] = (__bf16)v;
        }
        bfrag[ky] = bv;
    }
    const float b = bias[0];

    // per-thread staging coords (step-invariant): granule g = k*256 + tid
    int srow[NLD], scol[NLD];
    #pragma unroll
    for (int k = 0; k < NLD; ++k) {
        const int g = k*256 + tid;
        srow[k] = g / GPR;
        scol[k] = (g - srow[k]*GPR) * 4;       // float col
    }

    // ---- prologue: stage step-0 tile (fp32 load -> bf16 -> LDS) ----
    {
        float4 ld[NLD];
        #pragma unroll
        for (int k = 0; k < NLD; ++k) {
            if (k*256 + tid < NGRAN) {
                int r = ybase + srow[k], c = X0 + scol[k];
                if (GUARD) { r = min(r, IN_N-1); c = min(c, IN_N-4); }
                ld[k] = *(const float4*)(X + (size_t)r * IN_N + c);
            }
        }
        #pragma unroll
        for (int k = 0; k < NLD; ++k) {
            if (k*256 + tid < NGRAN) {
                ushort4 h;
                h.x = f2bf(ld[k].x); h.y = f2bf(ld[k].y);
                h.z = f2bf(ld[k].z); h.w = f2bf(ld[k].w);
                *(ushort4*)( (k & 1 ? sb0 : sb0) + srow[k]*LSTR + scol[k]*2 ) = h;
            }
        }
    }
    asm volatile("s_waitcnt lgkmcnt(0)" ::: "memory");
    __builtin_amdgcn_s_barrier();
    __builtin_amdgcn_sched_barrier(0);

    // ---- 4-step walk, double-buffered; stores never drained in-loop ----
    #pragma unroll
    for (int t = 0; t < NSTEP; ++t) {
        char* cur = (t & 1) ? sb1 : sb0;
        char* nxt = (t & 1) ? sb0 : sb1;
        const int y0 = ybase + t * BYO;

        // issue next-tile loads EARLY (latency hides under MFMA+stores)
        float4 ld[NLD];
        if (t + 1 < NSTEP) {
            const int yn = y0 + BYO;
            #pragma unroll
            for (int k = 0; k < NLD; ++k) {
                if (k*256 + tid < NGRAN) {
                    int r = yn + srow[k], c = X0 + scol[k];
                    if (GUARD) { r = min(r, IN_N-1); c = min(c, IN_N-4); }
                    ld[k] = *(const float4*)(X + (size_t)r * IN_N + c);
                }
            }
        }

        // compute 8 x-tiles: 7 MFMA each, acc init = bias
        const char* abase = cur + (16*w + lo) * LSTR + 16*hi;
        float* obase = out + (size_t)(y0 + 16*w + 4*hi) * OUT_N + (X0 + lo);
        #pragma unroll
        for (int t8 = 0; t8 < 8; ++t8) {
            f32x4 acc = { b, b, b, b };
            #pragma unroll
            for (int ky = 0; ky < KS; ++ky) {
                bf16x8 a = *(const bf16x8*)(abase + ky*LSTR + 32*t8);
                acc = __builtin_amdgcn_mfma_f32_16x16x32_bf16(a, bfrag[ky], acc, 0, 0, 0);
            }
            if (GUARD) {
                const int ox = X0 + 16*t8 + lo;
                if (ox < OUT_N) {
                    #pragma unroll
                    for (int r = 0; r < 4; ++r) {
                        const int oy = y0 + 16*w + 4*hi + r;
                        if (oy < OUT_N) obase[(size_t)r*OUT_N + 16*t8] = acc[r];
                    }
                }
            } else {
                #pragma unroll
                for (int r = 0; r < 4; ++r)
                    obase[(size_t)r*OUT_N + 16*t8] = acc[r];
            }
        }

        // convert + LDS-write next tile, one barrier per step
        if (t + 1 < NSTEP) {
            #pragma unroll
            for (int k = 0; k < NLD; ++k) {
                if (k*256 + tid < NGRAN) {
                    ushort4 h;
                    h.x = f2bf(ld[k].x); h.y = f2bf(ld[k].y);
                    h.z = f2bf(ld[k].z); h.w = f2bf(ld[k].w);
                    *(ushort4*)(nxt + srow[k]*LSTR + scol[k]*2) = h;
                }
            }
            asm volatile("s_waitcnt lgkmcnt(0)" ::: "memory");
            __builtin_amdgcn_s_barrier();
            __builtin_amdgcn_sched_barrier(0);
        }
    }
}

__global__ __launch_bounds__(256, 3)
void conv7x7_mfma(const float* __restrict__ X, const float* __restrict__ Kw,
                  const float* __restrict__ bias, float* __restrict__ out) {
    __shared__ __align__(16) char sb[2][IR * LSTR];   // 2 x 21280 B = 42.6 KB -> 3 blocks/CU
    const int tid = threadIdx.x;

    // XCD swizzle: XCD x gets segs [4x,4x+4), strips walked consecutively within it
    const int bid = blockIdx.x;                       // 0..2047
    const int swz = (bid & 7) * (NSTRIP * NSEG / 8) + (bid >> 3);
    const int strip = swz & (NSTRIP - 1);
    const int seg   = swz >> 6;
    const int X0    = strip * BXO;
    const int ybase = seg * (BYO * NSTEP);

    if (strip == NSTRIP-1 || seg == NSEG-1)
        run_block<true >(X, Kw, bias, out, sb[0], sb[1], X0, ybase, tid);
    else
        run_block<false>(X, Kw, bias, out, sb[0], sb[1], X0, ybase, tid);
}

extern "C" void kernel_launch(void* const* d_in, const int* in_sizes, int n_in,
                              void* d_out, int out_size, void* d_ws, size_t ws_size,
                              hipStream_t stream) {
    const float* X    = (const float*)d_in[0];
    const float* Kw   = (const float*)d_in[1];
    const float* bias = (const float*)d_in[2];
    float* out = (float*)d_out;

    conv7x7_mfma<<<dim3(NSTRIP * NSEG), dim3(256), 0, stream>>>(X, Kw, bias, out);
}